// Round 2
// baseline (480.491 us; speedup 1.0000x reference)
//
#include <hip/hip_runtime.h>

// LinearAttention bf16-MFMA pipeline.
// R11 change vs R10: 256x256/8-wave/128KB-LDS block replaced by
// 128x128/4-wave/64KB-LDS block -> 2 independent blocks per CU.
// Rationale: R9 vs R10 were identical (~1940 cy/phase, MfmaUtil 27%) despite
// opposite intra-phase schedules => stall is schedule-insensitive; all pipes
// <30% busy => lockstep barrier-chain of the SINGLE resident block (LDS 128KB
// and 256 unified regs/wave both capped occupancy at 1 block/CU). Two
// co-resident blocks have independent barrier domains; one block's MFMA fills
// the other's drain/latency bubbles (m97's 128^2 multi-block structure: 912 TF
// vs our 660 at 256^2). Kept proven pieces: 16B-XOR LDS swizzle (0 conflicts),
// global_load_lds width-16, counted prefetch (stage t+1 at tile-top, drained
// after 32 MFMAs), XCD-bijective swizzle, setprio, sched_barrier(0) after each
// lgkmcnt(0) (rule #18: MFMAs here consume same-tile ds_reads).
//
// B=8, S=4096, D=1024, F=1024.
// out[b,f,s] = sum_g ctxRaw[b,f,g] * Qs[b,s,g]
//   ctxRaw = K^T V (unscaled);  Qs = (relu(x@Wq)+1)/(den+eps)
//   den[b,g] = sum_s K[b,s,g];  K = relu(x@Wk)+1;  V = x@Wv
// All GEMMs: C[M][N] = sum_k A[M][K] * Bt[N][K]  (NT, both row-major bf16).
//
// Per-K-tile ledger (buf = t&1):
//   [BAR(t-1)] STAGE(t+1 -> buf^1) (8 gld_lds16)   ; WAR: buf^1 last read at
//              tile t-1 kk1, lgkm-drained before BAR(t-1) by every wave.
//   LD(a0,b0 kk0 from buf); lgkm(0); SB; MM16(kk0)
//   LD(a1,b1 kk1 from buf); lgkm(0); SB; MM16(kk1)   (reads overlap MM16(kk0))
//   vmcnt(0)  ; drains STAGE(t+1) issued ~[reads+32 MFMA] earlier
//   SB; BAR   ; publishes buf^1 to all waves before any tile-t+1 read.
// Prologue: STAGE(0) only; vmcnt(0); BAR (first tile eats full latency once;
// the co-resident block hides it).

#define EPSF 1e-6f

constexpr int Bb = 8;
constexpr int Ss = 4096;
constexpr int Dd = 1024;
constexpr int Ff = 1024;

typedef __attribute__((ext_vector_type(8))) short   bf16x8;
typedef __attribute__((ext_vector_type(8))) unsigned short u16x8;
typedef __attribute__((ext_vector_type(4))) float   f32x4;

// explicit LDS (addrspace 3) pointer types
typedef __attribute__((address_space(3))) unsigned char lds_u8;
typedef __attribute__((address_space(3))) const bf16x8  lds_cvec;

static __device__ __forceinline__ unsigned short f2bf(float f) {
    union { float f; unsigned int u; } v; v.f = f;
    unsigned int r = (v.u + 0x7fffu + ((v.u >> 16) & 1u)) >> 16;
    return (unsigned short)r;
}
static __device__ __forceinline__ float bf2f(unsigned short u) {
    union { unsigned int u; float f; } v; v.u = ((unsigned int)u) << 16;
    return v.f;
}

static __device__ __forceinline__ void gld_lds16(const void* g, lds_u8* l) {
    __builtin_amdgcn_global_load_lds(
        (const __attribute__((address_space(1))) unsigned int*)g,
        (__attribute__((address_space(3))) unsigned int*)l,
        16, 0, 0);
}

// ---------------------------------------------------------------------------
__global__ void cvt_x_kernel(const float* __restrict__ x, unsigned short* __restrict__ xb, int n4)
{
    int i = blockIdx.x * blockDim.x + threadIdx.x;
    if (i >= n4) return;
    float4 v = *(const float4*)&x[(size_t)i * 4];
    ushort4 o;
    o.x = f2bf(v.x); o.y = f2bf(v.y); o.z = f2bf(v.z); o.w = f2bf(v.w);
    *(ushort4*)&xb[(size_t)i * 4] = o;
}

// W[d][f] fp32 -> WT[f][d] bf16 (x3 weights)
__global__ void cvt_wT_kernel(const float* __restrict__ Wq,
                              const float* __restrict__ Wk,
                              const float* __restrict__ Wv,
                              unsigned short* __restrict__ WT)
{
    const int z = blockIdx.z;
    const float* __restrict__ W = (z == 0) ? Wq : (z == 1 ? Wk : Wv);
    unsigned short* __restrict__ dst = WT + (size_t)z * Dd * Ff;

    __shared__ float tile[32][33];
    const int tid = threadIdx.x;
    const int d0 = blockIdx.y * 32, f0 = blockIdx.x * 32;
    const int c = tid & 31, r8 = tid >> 5;
#pragma unroll
    for (int p = 0; p < 4; ++p) {
        int r = p * 8 + r8;
        tile[r][c] = W[(size_t)(d0 + r) * Ff + f0 + c];
    }
    __syncthreads();
#pragma unroll
    for (int p = 0; p < 4; ++p) {
        int r = p * 8 + r8;
        dst[(size_t)(f0 + r) * Dd + d0 + c] = f2bf(tile[c][r]);
    }
}

// den[b][f] = sum_s KbT[b][f][s]
__global__ void den_kernel(const unsigned short* __restrict__ KbT, float* __restrict__ den)
{
    const int tid = threadIdx.x;
    const int w = tid >> 6, lane = tid & 63;
    const int f = blockIdx.x * 4 + w;
    const int b = blockIdx.y;
    const unsigned short* __restrict__ row = KbT + ((size_t)b * Ff + f) * Ss;
    float s = 0.f;
#pragma unroll
    for (int it = 0; it < Ss / 512; ++it) {
        u16x8 v = *(const u16x8*)&row[it * 512 + lane * 8];
#pragma unroll
        for (int j = 0; j < 8; ++j) s += bf2f(v[j]);
    }
#pragma unroll
    for (int off = 32; off > 0; off >>= 1) s += __shfl_down(s, off, 64);
    if (lane == 0) den[(size_t)b * Ff + f] = s;
}

// ctx[b] = p[2b] + p[2b+1]  (bf16 split-K partials)
__global__ void add_ctx_kernel(const unsigned short* __restrict__ p,
                               unsigned short* __restrict__ c)
{
    const int b = blockIdx.y;
    const size_t i8 = ((size_t)blockIdx.x * 256 + threadIdx.x) * 8;
    const u16x8 a0 = *(const u16x8*)(p + (size_t)(2 * b) * Ff * Ff + i8);
    const u16x8 a1 = *(const u16x8*)(p + (size_t)(2 * b + 1) * Ff * Ff + i8);
    u16x8 o;
#pragma unroll
    for (int j = 0; j < 8; ++j) o[j] = f2bf(bf2f(a0[j]) + bf2f(a1[j]));
    *(u16x8*)(c + (size_t)b * Ff * Ff + i8) = o;
}

// ---------------------------------------------------------------------------
// 128x128 NT bf16 MFMA GEMM, 256 threads, 4 waves (2M x 2N), BK=64.
// LDS: buf0.A@0 buf0.B@16K buf1.A@32K buf1.B@48K; each [128 rows][128B],
// 16B-chunk XOR-swizzle key=(row&7). MFMA swapped operands (C^T frags).
// 64KB LDS -> 2 blocks/CU (independent barrier domains = latency hiding).
template<int ACT, int SCALE, int OUT_BF16, int SPLITK2>
__global__ __launch_bounds__(256, 2)
void gemm8(const unsigned short* __restrict__ A,
           const unsigned short* __restrict__ Bt,
           void* __restrict__ Cout,
           const float* __restrict__ den,
           int lda, int ldb, int ldc, int Kdim,
           size_t strideA, size_t strideB, size_t strideC)
{
    __shared__ __align__(16) unsigned char smem_[65536];
    lds_u8* const smem = (lds_u8*)smem_;

    // ---- XCD-aware bijective block swizzle (total blocks % 8 == 0 always)
    const int gx = gridDim.x, gxy = gx * gridDim.y;
    int flat = blockIdx.z * gxy + blockIdx.y * gx + blockIdx.x;
    const int nwg = gxy * gridDim.z;
    const int cpx = nwg >> 3;
    flat = (flat & 7) * cpx + (flat >> 3);
    const int z = flat / gxy;
    const int rem = flat - z * gxy;
    const int by = rem / gx;
    const int bx = rem - by * gx;

    const int zb   = SPLITK2 ? (z >> 1) : z;
    const int koff = SPLITK2 ? ((z & 1) * Kdim) : 0;

    const unsigned short* __restrict__ Ag  = A  + strideA * zb + koff;
    const unsigned short* __restrict__ Bg  = Bt + strideB * zb + koff;
    const float* __restrict__ denb = SCALE ? (den + (size_t)zb * Ff) : nullptr;

    const int bm = by * 128;
    const int bn = bx * 128;

    const int tid  = threadIdx.x;
    const int wv   = tid >> 6, lane = tid & 63;
    const int wm   = wv >> 1, wn = wv & 1;        // 2 x 2 wave grid
    const int lm   = lane & 15;
    const int kg16 = (lane >> 4) << 4;            // k-group byte offset
    const int swz  = (lm & 7) << 4;               // read-side XOR key (row&7)
    const int kbs  = (((tid & 7) ^ ((tid >> 3) & 7)) << 4);  // stage src chunk
    const int srow = tid >> 3;                    // stage row within 32-row q-block

    f32x4 acc[4][4];
#pragma unroll
    for (int i = 0; i < 4; ++i)
#pragma unroll
        for (int j = 0; j < 4; ++j) acc[i][j] = (f32x4){0.f, 0.f, 0.f, 0.f};

    // stage one matrix (16KB, 4 gld_lds16/thread) of K-tile ts into buf.
    // m: 0=A 1=B. LDS dest is linear (wave-uniform base + lane*16); global
    // source chunk is inverse-XOR-swizzled so read-side XOR sees global data.
    auto STAGE = [&](int ts, int m, int buf) {
        const unsigned short* gb = m ? Bg : Ag;
        const int ld = m ? ldb : lda;
        const int off0 = m ? bn : bm;
        lds_u8* lb = smem + buf * 32768 + m * 16384 + wv * 1024;
#pragma unroll
        for (int q = 0; q < 4; ++q) {
            int row = q * 32 + srow;
            const unsigned char* g =
                (const unsigned char*)(gb + (size_t)(off0 + row) * ld + ts * 64) + kbs;
            gld_lds16(g, lb + q * 4096);
        }
    };
    // read 4 MFMA fragments (rows w0*64 + f*16 + lm) of k-half kk from base.
    auto LD4 = [&](bf16x8* dst, int kk, lds_u8* base, int w0) {
#pragma unroll
        for (int f = 0; f < 4; ++f) {
            int r = w0 * 64 + f * 16 + lm;
            dst[f] = *(lds_cvec*)(base + r * 128 + ((kk * 64 + kg16) ^ swz));
        }
    };

    // swapped operands: D frag = C^T block (rows=N, cols=M)
#define MM16(a4, b4)                                                            \
    do {                                                                        \
        __builtin_amdgcn_s_setprio(1);                                          \
        _Pragma("unroll")                                                       \
        for (int fm = 0; fm < 4; ++fm)                                          \
            _Pragma("unroll")                                                   \
            for (int fn = 0; fn < 4; ++fn)                                      \
                acc[fm][fn] = __builtin_amdgcn_mfma_f32_16x16x32_bf16(          \
                    (b4)[fn], (a4)[fm], acc[fm][fn], 0, 0, 0);                  \
        __builtin_amdgcn_s_setprio(0);                                          \
    } while (0)

#define LGKM0_FENCE()                                               \
    do {                                                            \
        asm volatile("s_waitcnt lgkmcnt(0)");                       \
        __builtin_amdgcn_sched_barrier(0);                          \
    } while (0)

    const int NT = Kdim >> 6;   // K-tiles of 64 (>= 16 here)

    // prologue: tile 0 -> buf0
    STAGE(0, 0, 0); STAGE(0, 1, 0);
    asm volatile("s_waitcnt vmcnt(0)");
    __builtin_amdgcn_s_barrier();

    for (int t = 0; t < NT; ++t) {
        const int buf = t & 1;
        lds_u8* Ab  = smem + buf * 32768;
        lds_u8* Bbs = Ab + 16384;
        if (t + 1 < NT) {                    // prefetch next tile -> other buf
            STAGE(t + 1, 0, buf ^ 1);
            STAGE(t + 1, 1, buf ^ 1);
        }
        bf16x8 a0[4], b0r[4], a1[4], b1r[4];
        LD4(a0, 0, Ab, wm); LD4(b0r, 0, Bbs, wn);
        LGKM0_FENCE();
        MM16(a0, b0r);                       // kk1 reads below may overlap this
        LD4(a1, 1, Ab, wm); LD4(b1r, 1, Bbs, wn);
        LGKM0_FENCE();
        MM16(a1, b1r);
        asm volatile("s_waitcnt vmcnt(0)");  // next tile landed (issued ~32 MFMAs ago)
        __builtin_amdgcn_sched_barrier(0);
        __builtin_amdgcn_s_barrier();        // publish buf^1 to all waves
    }

    // ---- epilogue (swapped layout): frag (fm,fn):
    // row m = bm + wm*64 + fm*16 + lm ; cols n = bn + wn*64 + fn*16 + (lane>>4)*4
    const int hi4 = (lane >> 4) * 4;
#pragma unroll
    for (int fm = 0; fm < 4; ++fm) {
        const int gr = bm + wm * 64 + fm * 16 + lm;
#pragma unroll
        for (int fn = 0; fn < 4; ++fn) {
            const int gcn = bn + wn * 64 + fn * 16 + hi4;
            f32x4 v = acc[fm][fn];
            if (ACT) {
#pragma unroll
                for (int e = 0; e < 4; ++e) v[e] = fmaxf(v[e], 0.f) + 1.f;
            }
            if (SCALE) {
                float4 d4 = *(const float4*)&denb[gcn];
                v[0] *= 1.f / (d4.x + EPSF);
                v[1] *= 1.f / (d4.y + EPSF);
                v[2] *= 1.f / (d4.z + EPSF);
                v[3] *= 1.f / (d4.w + EPSF);
            }
            if (OUT_BF16) {
                ushort4 o;
                o.x = f2bf(v[0]); o.y = f2bf(v[1]); o.z = f2bf(v[2]); o.w = f2bf(v[3]);
                *(ushort4*)((unsigned short*)Cout + strideC * z + (size_t)gr * ldc + gcn) = o;
            } else {
                *(float4*)((float*)Cout + strideC * z + (size_t)gr * ldc + gcn) =
                    *(float4*)&v;
            }
        }
    }
#undef MM16
#undef LGKM0_FENCE
}

// ---------------------------------------------------------------------------
extern "C" void kernel_launch(void* const* d_in, const int* in_sizes, int n_in,
                              void* d_out, int out_size, void* d_ws, size_t ws_size,
                              hipStream_t stream)
{
    (void)in_sizes; (void)n_in; (void)out_size;
    const float* x  = (const float*)d_in[0];
    const float* Wq = (const float*)d_in[1];
    const float* Wk = (const float*)d_in[2];
    const float* Wv = (const float*)d_in[3];
    float* out = (float*)d_out;

    const size_t nx   = (size_t)Bb * Ss * Dd;
    const size_t nW   = (size_t)3 * Dd * Ff;
    const size_t nQKV = (size_t)Bb * Ss * Ff;
    const size_t nCtx = (size_t)Bb * Ff * Ff;
    const size_t nP   = (size_t)16 * Ff * Ff;   // split-K partials (bf16)

    unsigned short* xb   = (unsigned short*)d_ws;          // [B][S][D]
    unsigned short* WT   = xb + nx;                        // [3][F][D]
    unsigned short* Qb   = WT + nW;                        // [B][S][F] (den-scaled)
    unsigned short* KbT  = Qb + nQKV;                      // [B][F][S]
    unsigned short* VbT  = KbT + nQKV;                     // [B][F][S]
    unsigned short* ctxb = VbT + nQKV;                     // [B][F][F]
    float* den = (float*)(ctxb + nCtx);                    // [B][F]
    unsigned short* pctx = (unsigned short*)(den + (size_t)Bb * Ff); // [16][F][F]

    const size_t need_split =
        ((nx + nW + 3 * nQKV + nCtx + nP) * 2 + (size_t)Bb * Ff * 4);
    const bool do_split = ws_size >= need_split;

    cvt_x_kernel<<<dim3((int)(nx / 4 / 256)), 256, 0, stream>>>(x, xb, (int)(nx / 4));
    cvt_wT_kernel<<<dim3(Ff / 32, Dd / 32, 3), 256, 0, stream>>>(Wq, Wk, Wv, WT);

    // K^T[f][s] = relu1(WkT @ x^T): A=WTk [F][D], Bt=xb [S][D]
    gemm8<1, 0, 1, 0><<<dim3(Ss / 128, Ff / 128, Bb), 256, 0, stream>>>(
        WT + (size_t)1 * Dd * Ff, xb, KbT, nullptr,
        Dd, Dd, Ss, Dd, 0, (size_t)Ss * Dd, (size_t)Ff * Ss);

    // den[b][f] = sum_s K^T[f][s]
    den_kernel<<<dim3(Ff / 4, Bb), 256, 0, stream>>>(KbT, den);

    // Qs[s][f] = relu1(x @ Wq) / (den[f]+eps)
    gemm8<1, 1, 1, 0><<<dim3(Ff / 128, Ss / 128, Bb), 256, 0, stream>>>(
        xb, WT + (size_t)0 * Dd * Ff, Qb, den,
        Dd, Dd, Ff, Dd, (size_t)Ss * Dd, 0, (size_t)Ss * Ff);

    // V^T[g][s]
    gemm8<0, 0, 1, 0><<<dim3(Ss / 128, Ff / 128, Bb), 256, 0, stream>>>(
        WT + (size_t)2 * Dd * Ff, xb, VbT, nullptr,
        Dd, Dd, Ss, Dd, 0, (size_t)Ss * Dd, (size_t)Ff * Ss);

    // ctxRaw[f][g] = K^T V  (split-K=2)
    if (do_split) {
        gemm8<0, 0, 1, 1><<<dim3(Ff / 128, Ff / 128, 2 * Bb), 256, 0, stream>>>(
            KbT, VbT, pctx, nullptr,
            Ss, Ss, Ff, Ss / 2, (size_t)Ff * Ss, (size_t)Ff * Ss, (size_t)Ff * Ff);
        add_ctx_kernel<<<dim3(Ff * Ff / 8 / 256, Bb), 256, 0, stream>>>(pctx, ctxb);
    } else {
        gemm8<0, 0, 1, 0><<<dim3(Ff / 128, Ff / 128, Bb), 256, 0, stream>>>(
            KbT, VbT, ctxb, nullptr,
            Ss, Ss, Ff, Ss, (size_t)Ff * Ss, (size_t)Ff * Ss, (size_t)Ff * Ff);
    }

    // out[f][s] = ctxRaw @ Qs^T (fp32 out)
    gemm8<0, 0, 0, 0><<<dim3(Ss / 128, Ff / 128, Bb), 256, 0, stream>>>(
        ctxb, Qb, out, nullptr,
        Ff, Ff, Ss, Ff, (size_t)Ff * Ff, (size_t)Ss * Ff, (size_t)Ff * Ss);
}

// Round 3
// 442.224 us; speedup vs baseline: 1.0865x; 1.0865x over previous
//
#include <hip/hip_runtime.h>

// LinearAttention bf16-MFMA pipeline.
// R12: exact m97 structure (874-912 TF measured on gfx950 at 4096^3).
// 128x128 tile, BK=64, SINGLE 32KB LDS buffer, two __syncthreads per K-tile
// (stage -> sync[drains vmcnt] -> ds_read+MFMA -> sync), no prefetch, no
// counted vmcnt, no setprio (m190: hurts lockstep), no sched_barrier.
// __launch_bounds__(256,3): ~164 unified regs -> 3 blocks/CU; the 3
// co-resident blocks cover each tile's stage-drain stall (the mechanism R11's
// 64KB/2-block dbuf variant lacked).
// Rationale: R9/R10/R11 all sit at the "2-phase plateau" (~600-680 TF, m233/
// m230) regardless of schedule => stop re-deriving the 8-phase; take the
// proven simple structure with occupancy-3 latency hiding.
// Kept verified pieces from R11: STAGE/LD4 index math + 16B-chunk XOR swizzle
// (0 bank conflicts), gld_lds16 width-16 staging, XCD-bijective block swizzle,
// epilogue mapping, split-K=2 for the KV GEMM.
//
// B=8, S=4096, D=1024, F=1024.
// out[b,f,s] = sum_g ctxRaw[b,f,g] * Qs[b,s,g]
//   ctxRaw = K^T V (unscaled);  Qs = (relu(x@Wq)+1)/(den+eps)
//   den[b,g] = sum_s K[b,s,g];  K = relu(x@Wk)+1;  V = x@Wv
// All GEMMs: C[M][N] = sum_k A[M][K] * Bt[N][K]  (NT, both row-major bf16).

#define EPSF 1e-6f

constexpr int Bb = 8;
constexpr int Ss = 4096;
constexpr int Dd = 1024;
constexpr int Ff = 1024;

typedef __attribute__((ext_vector_type(8))) short   bf16x8;
typedef __attribute__((ext_vector_type(8))) unsigned short u16x8;
typedef __attribute__((ext_vector_type(4))) float   f32x4;

// explicit LDS (addrspace 3) pointer types
typedef __attribute__((address_space(3))) unsigned char lds_u8;
typedef __attribute__((address_space(3))) const bf16x8  lds_cvec;

static __device__ __forceinline__ unsigned short f2bf(float f) {
    union { float f; unsigned int u; } v; v.f = f;
    unsigned int r = (v.u + 0x7fffu + ((v.u >> 16) & 1u)) >> 16;
    return (unsigned short)r;
}
static __device__ __forceinline__ float bf2f(unsigned short u) {
    union { unsigned int u; float f; } v; v.u = ((unsigned int)u) << 16;
    return v.f;
}

static __device__ __forceinline__ void gld_lds16(const void* g, lds_u8* l) {
    __builtin_amdgcn_global_load_lds(
        (const __attribute__((address_space(1))) unsigned int*)g,
        (__attribute__((address_space(3))) unsigned int*)l,
        16, 0, 0);
}

// ---------------------------------------------------------------------------
__global__ void cvt_x_kernel(const float* __restrict__ x, unsigned short* __restrict__ xb, int n4)
{
    int i = blockIdx.x * blockDim.x + threadIdx.x;
    if (i >= n4) return;
    float4 v = *(const float4*)&x[(size_t)i * 4];
    ushort4 o;
    o.x = f2bf(v.x); o.y = f2bf(v.y); o.z = f2bf(v.z); o.w = f2bf(v.w);
    *(ushort4*)&xb[(size_t)i * 4] = o;
}

// W[d][f] fp32 -> WT[f][d] bf16 (x3 weights)
__global__ void cvt_wT_kernel(const float* __restrict__ Wq,
                              const float* __restrict__ Wk,
                              const float* __restrict__ Wv,
                              unsigned short* __restrict__ WT)
{
    const int z = blockIdx.z;
    const float* __restrict__ W = (z == 0) ? Wq : (z == 1 ? Wk : Wv);
    unsigned short* __restrict__ dst = WT + (size_t)z * Dd * Ff;

    __shared__ float tile[32][33];
    const int tid = threadIdx.x;
    const int d0 = blockIdx.y * 32, f0 = blockIdx.x * 32;
    const int c = tid & 31, r8 = tid >> 5;
#pragma unroll
    for (int p = 0; p < 4; ++p) {
        int r = p * 8 + r8;
        tile[r][c] = W[(size_t)(d0 + r) * Ff + f0 + c];
    }
    __syncthreads();
#pragma unroll
    for (int p = 0; p < 4; ++p) {
        int r = p * 8 + r8;
        dst[(size_t)(f0 + r) * Dd + d0 + c] = f2bf(tile[c][r]);
    }
}

// den[b][f] = sum_s KbT[b][f][s]
__global__ void den_kernel(const unsigned short* __restrict__ KbT, float* __restrict__ den)
{
    const int tid = threadIdx.x;
    const int w = tid >> 6, lane = tid & 63;
    const int f = blockIdx.x * 4 + w;
    const int b = blockIdx.y;
    const unsigned short* __restrict__ row = KbT + ((size_t)b * Ff + f) * Ss;
    float s = 0.f;
#pragma unroll
    for (int it = 0; it < Ss / 512; ++it) {
        u16x8 v = *(const u16x8*)&row[it * 512 + lane * 8];
#pragma unroll
        for (int j = 0; j < 8; ++j) s += bf2f(v[j]);
    }
#pragma unroll
    for (int off = 32; off > 0; off >>= 1) s += __shfl_down(s, off, 64);
    if (lane == 0) den[(size_t)b * Ff + f] = s;
}

// ctx[b] = p[2b] + p[2b+1]  (bf16 split-K partials)
__global__ void add_ctx_kernel(const unsigned short* __restrict__ p,
                               unsigned short* __restrict__ c)
{
    const int b = blockIdx.y;
    const size_t i8 = ((size_t)blockIdx.x * 256 + threadIdx.x) * 8;
    const u16x8 a0 = *(const u16x8*)(p + (size_t)(2 * b) * Ff * Ff + i8);
    const u16x8 a1 = *(const u16x8*)(p + (size_t)(2 * b + 1) * Ff * Ff + i8);
    u16x8 o;
#pragma unroll
    for (int j = 0; j < 8; ++j) o[j] = f2bf(bf2f(a0[j]) + bf2f(a1[j]));
    *(u16x8*)(c + (size_t)b * Ff * Ff + i8) = o;
}

// ---------------------------------------------------------------------------
// 128x128 NT bf16 MFMA GEMM, 256 threads, 4 waves (2M x 2N), BK=64.
// SINGLE LDS buffer: A@0 B@16K; each [128 rows][128B], 16B-chunk XOR-swizzle
// key=(row&7). MFMA swapped operands (C^T frags). m97 sync discipline:
//   STAGE(t) ; __syncthreads() ; LD+MFMA ; __syncthreads()
// 32KB LDS + <=170 regs -> 3 blocks/CU; blocks cover each other's drains.
template<int ACT, int SCALE, int OUT_BF16, int SPLITK2>
__global__ __launch_bounds__(256, 3)
void gemm8(const unsigned short* __restrict__ A,
           const unsigned short* __restrict__ Bt,
           void* __restrict__ Cout,
           const float* __restrict__ den,
           int lda, int ldb, int ldc, int Kdim,
           size_t strideA, size_t strideB, size_t strideC)
{
    __shared__ __align__(16) unsigned char smem_[32768];
    lds_u8* const smem = (lds_u8*)smem_;

    // ---- XCD-aware bijective block swizzle (total blocks % 8 == 0 always)
    const int gx = gridDim.x, gxy = gx * gridDim.y;
    int flat = blockIdx.z * gxy + blockIdx.y * gx + blockIdx.x;
    const int nwg = gxy * gridDim.z;
    const int cpx = nwg >> 3;
    flat = (flat & 7) * cpx + (flat >> 3);
    const int z = flat / gxy;
    const int rem = flat - z * gxy;
    const int by = rem / gx;
    const int bx = rem - by * gx;

    const int zb   = SPLITK2 ? (z >> 1) : z;
    const int koff = SPLITK2 ? ((z & 1) * Kdim) : 0;

    const unsigned short* __restrict__ Ag  = A  + strideA * zb + koff;
    const unsigned short* __restrict__ Bg  = Bt + strideB * zb + koff;
    const float* __restrict__ denb = SCALE ? (den + (size_t)zb * Ff) : nullptr;

    const int bm = by * 128;
    const int bn = bx * 128;

    const int tid  = threadIdx.x;
    const int wv   = tid >> 6, lane = tid & 63;
    const int wm   = wv >> 1, wn = wv & 1;        // 2 x 2 wave grid
    const int lm   = lane & 15;
    const int kg16 = (lane >> 4) << 4;            // k-group byte offset
    const int swz  = (lm & 7) << 4;               // read-side XOR key (row&7)
    const int kbs  = (((tid & 7) ^ ((tid >> 3) & 7)) << 4);  // stage src chunk
    const int srow = tid >> 3;                    // stage row within 32-row q-block

    f32x4 acc[4][4];
#pragma unroll
    for (int i = 0; i < 4; ++i)
#pragma unroll
        for (int j = 0; j < 4; ++j) acc[i][j] = (f32x4){0.f, 0.f, 0.f, 0.f};

    lds_u8* const Ab  = smem;
    lds_u8* const Bbs = smem + 16384;

    // stage one matrix (16KB, 4 gld_lds16/thread) of K-tile ts.
    // m: 0=A 1=B. LDS dest is linear (wave-uniform base + lane*16); global
    // source chunk is inverse-XOR-swizzled so read-side XOR sees global data.
    auto STAGE = [&](int ts, int m) {
        const unsigned short* gb = m ? Bg : Ag;
        const int ld = m ? ldb : lda;
        const int off0 = m ? bn : bm;
        lds_u8* lb = smem + m * 16384 + wv * 1024;
#pragma unroll
        for (int q = 0; q < 4; ++q) {
            int row = q * 32 + srow;
            const unsigned char* g =
                (const unsigned char*)(gb + (size_t)(off0 + row) * ld + ts * 64) + kbs;
            gld_lds16(g, lb + q * 4096);
        }
    };
    // read 4 MFMA fragments (rows w0*64 + f*16 + lm) of k-half kk from base.
    auto LD4 = [&](bf16x8* dst, int kk, lds_u8* base, int w0) {
#pragma unroll
        for (int f = 0; f < 4; ++f) {
            int r = w0 * 64 + f * 16 + lm;
            dst[f] = *(lds_cvec*)(base + r * 128 + ((kk * 64 + kg16) ^ swz));
        }
    };

    // swapped operands: D frag = C^T block (rows=N, cols=M)
#define MM16(a4, b4)                                                            \
    do {                                                                        \
        _Pragma("unroll")                                                       \
        for (int fm = 0; fm < 4; ++fm)                                          \
            _Pragma("unroll")                                                   \
            for (int fn = 0; fn < 4; ++fn)                                      \
                acc[fm][fn] = __builtin_amdgcn_mfma_f32_16x16x32_bf16(          \
                    (b4)[fn], (a4)[fm], acc[fm][fn], 0, 0, 0);                  \
    } while (0)

    const int NT = Kdim >> 6;   // K-tiles of 64 (>= 16 here)

    for (int t = 0; t < NT; ++t) {
        STAGE(t, 0);
        STAGE(t, 1);
        __syncthreads();                     // drains vmcnt(0)+lgkmcnt(0); publishes tile
        bf16x8 a0[4], b0r[4], a1[4], b1r[4];
        LD4(a0, 0, Ab, wm); LD4(b0r, 0, Bbs, wn);
        MM16(a0, b0r);
        LD4(a1, 1, Ab, wm); LD4(b1r, 1, Bbs, wn);
        MM16(a1, b1r);
        __syncthreads();                     // all reads done; safe to re-stage
    }

    // ---- epilogue (swapped layout): frag (fm,fn):
    // row m = bm + wm*64 + fm*16 + lm ; cols n = bn + wn*64 + fn*16 + (lane>>4)*4
    const int hi4 = (lane >> 4) * 4;
#pragma unroll
    for (int fm = 0; fm < 4; ++fm) {
        const int gr = bm + wm * 64 + fm * 16 + lm;
#pragma unroll
        for (int fn = 0; fn < 4; ++fn) {
            const int gcn = bn + wn * 64 + fn * 16 + hi4;
            f32x4 v = acc[fm][fn];
            if (ACT) {
#pragma unroll
                for (int e = 0; e < 4; ++e) v[e] = fmaxf(v[e], 0.f) + 1.f;
            }
            if (SCALE) {
                float4 d4 = *(const float4*)&denb[gcn];
                v[0] *= 1.f / (d4.x + EPSF);
                v[1] *= 1.f / (d4.y + EPSF);
                v[2] *= 1.f / (d4.z + EPSF);
                v[3] *= 1.f / (d4.w + EPSF);
            }
            if (OUT_BF16) {
                ushort4 o;
                o.x = f2bf(v[0]); o.y = f2bf(v[1]); o.z = f2bf(v[2]); o.w = f2bf(v[3]);
                *(ushort4*)((unsigned short*)Cout + strideC * z + (size_t)gr * ldc + gcn) = o;
            } else {
                *(float4*)((float*)Cout + strideC * z + (size_t)gr * ldc + gcn) =
                    *(float4*)&v;
            }
        }
    }
#undef MM16
}

// ---------------------------------------------------------------------------
extern "C" void kernel_launch(void* const* d_in, const int* in_sizes, int n_in,
                              void* d_out, int out_size, void* d_ws, size_t ws_size,
                              hipStream_t stream)
{
    (void)in_sizes; (void)n_in; (void)out_size;
    const float* x  = (const float*)d_in[0];
    const float* Wq = (const float*)d_in[1];
    const float* Wk = (const float*)d_in[2];
    const float* Wv = (const float*)d_in[3];
    float* out = (float*)d_out;

    const size_t nx   = (size_t)Bb * Ss * Dd;
    const size_t nW   = (size_t)3 * Dd * Ff;
    const size_t nQKV = (size_t)Bb * Ss * Ff;
    const size_t nCtx = (size_t)Bb * Ff * Ff;
    const size_t nP   = (size_t)16 * Ff * Ff;   // split-K partials (bf16)

    unsigned short* xb   = (unsigned short*)d_ws;          // [B][S][D]
    unsigned short* WT   = xb + nx;                        // [3][F][D]
    unsigned short* Qb   = WT + nW;                        // [B][S][F] (den-scaled)
    unsigned short* KbT  = Qb + nQKV;                      // [B][F][S]
    unsigned short* VbT  = KbT + nQKV;                     // [B][F][S]
    unsigned short* ctxb = VbT + nQKV;                     // [B][F][F]
    float* den = (float*)(ctxb + nCtx);                    // [B][F]
    unsigned short* pctx = (unsigned short*)(den + (size_t)Bb * Ff); // [16][F][F]

    const size_t need_split =
        ((nx + nW + 3 * nQKV + nCtx + nP) * 2 + (size_t)Bb * Ff * 4);
    const bool do_split = ws_size >= need_split;

    cvt_x_kernel<<<dim3((int)(nx / 4 / 256)), 256, 0, stream>>>(x, xb, (int)(nx / 4));
    cvt_wT_kernel<<<dim3(Ff / 32, Dd / 32, 3), 256, 0, stream>>>(Wq, Wk, Wv, WT);

    // K^T[f][s] = relu1(WkT @ x^T): A=WTk [F][D], Bt=xb [S][D]
    gemm8<1, 0, 1, 0><<<dim3(Ss / 128, Ff / 128, Bb), 256, 0, stream>>>(
        WT + (size_t)1 * Dd * Ff, xb, KbT, nullptr,
        Dd, Dd, Ss, Dd, 0, (size_t)Ss * Dd, (size_t)Ff * Ss);

    // den[b][f] = sum_s K^T[f][s]
    den_kernel<<<dim3(Ff / 4, Bb), 256, 0, stream>>>(KbT, den);

    // Qs[s][f] = relu1(x @ Wq) / (den[f]+eps)
    gemm8<1, 1, 1, 0><<<dim3(Ff / 128, Ss / 128, Bb), 256, 0, stream>>>(
        xb, WT + (size_t)0 * Dd * Ff, Qb, den,
        Dd, Dd, Ff, Dd, (size_t)Ss * Dd, 0, (size_t)Ss * Ff);

    // V^T[g][s]
    gemm8<0, 0, 1, 0><<<dim3(Ss / 128, Ff / 128, Bb), 256, 0, stream>>>(
        WT + (size_t)2 * Dd * Ff, xb, VbT, nullptr,
        Dd, Dd, Ss, Dd, 0, (size_t)Ss * Dd, (size_t)Ff * Ss);

    // ctxRaw[f][g] = K^T V  (split-K=2)
    if (do_split) {
        gemm8<0, 0, 1, 1><<<dim3(Ff / 128, Ff / 128, 2 * Bb), 256, 0, stream>>>(
            KbT, VbT, pctx, nullptr,
            Ss, Ss, Ff, Ss / 2, (size_t)Ff * Ss, (size_t)Ff * Ss, (size_t)Ff * Ff);
        add_ctx_kernel<<<dim3(Ff * Ff / 8 / 256, Bb), 256, 0, stream>>>(pctx, ctxb);
    } else {
        gemm8<0, 0, 1, 0><<<dim3(Ff / 128, Ff / 128, Bb), 256, 0, stream>>>(
            KbT, VbT, ctxb, nullptr,
            Ss, Ss, Ff, Ss, (size_t)Ff * Ss, (size_t)Ff * Ss, (size_t)Ff * Ff);
    }

    // out[f][s] = ctxRaw @ Qs^T (fp32 out)
    gemm8<0, 0, 0, 0><<<dim3(Ss / 128, Ff / 128, Bb), 256, 0, stream>>>(
        ctxb, Qb, out, nullptr,
        Ff, Ff, Ss, Ff, (size_t)Ff * Ff, (size_t)Ss * Ff, (size_t)Ff * Ss);
}